// Round 11
// baseline (74.008 us; speedup 1.0000x reference)
//
#include <hip/hip_runtime.h>
#include <hip/hip_bf16.h>
#include <math.h>

#define XDIM 2048
#define OW   2033        // 2048 - 16 + 1
#define TR   32          // out rows per block tile
#define TC   256         // out cols per block tile (64 per wave)
#define WPC  80          // pair-cols per wave slice (64 + 16 halo)
#define PH   8           // rows per phase
#define NPH  24          // 4 channels * 6 phases

typedef __bf16 bf16x8 __attribute__((ext_vector_type(8)));
typedef float  f32x16 __attribute__((ext_vector_type(16)));

union U128 { uint4 u; bf16x8 v; };

__device__ __forceinline__ unsigned short bfbits(float f) {
    return __builtin_bit_cast(unsigned short, __float2bfloat16(f));
}
// pair word: low16 = bf16(x^2) (weight w), high16 = bf16(x) (weight -2wk)
__device__ __forceinline__ unsigned int packx(float f) {
    unsigned int r;
    asm("v_cvt_pk_bf16_f32 %0, %1, %2" : "=v"(r) : "v"(f * f), "v"(f));
    return r;
}
// XOR bank swizzle on PAIR index (bits 1..3 only): 16B write alignment kept,
// bijective on [0,80); r9/r10-proven conflict-clean for writes AND b64 reads.
__device__ __forceinline__ int slz(int c) { return c ^ (((c >> 2) & 7) << 1); }

__global__ __launch_bounds__(256) void psnr_mfma_kernel(
    const float* __restrict__ x,
    const float* __restrict__ kern,
    float* __restrict__ out)
{
    // WAVE-PRIVATE double-buffered 8-row rings: each staged row is read only
    // by the wave that wrote it -> ZERO barriers in the main loop. Intra-wave
    // LDS write->read ordering is compiler-inserted lgkmcnt.
    __shared__ __align__(16) uint2 wbuf[4][2][PH][WPC];           // 40.96 KB
    __shared__ __align__(16) unsigned int wt[4][17 * 20];         // 5.44 KB
    __shared__ float skkArr[4];

    const int tid  = threadIdx.x;
    const int lane = tid & 63;
    const int wv   = tid >> 6;         // wave 0..3
    const int nn   = lane & 31;        // m for A-frags, n for B-frags
    const int hf   = lane >> 5;        // k-block half

    const int r0  = blockIdx.y * TR;
    const int c0  = blockIdx.x * TC;
    const int c0w = c0 + (wv << 6);    // this wave's first out-col

    // ---- staging registers: 3 named float4 + 3 floats (static indexing) ----
    float4 pf0, pf1, pf2;
    float  pe0, pe1, pe2;

    auto ld1 = [&](int q, int ch, int it, float4& v4, float& v1) {
        unsigned int row = (unsigned int)it / 20u;     // item -> local row
        int cc = (it - (int)row * 20) * 4;             // item -> pair-col 0..76
        int gr = r0 + q * PH + (int)row; if (gr > XDIM - 1) gr = XDIM - 1;
        int gc = c0w + cc;
        const float* rp = x + ((size_t)ch << 22) + (size_t)gr * XDIM;
        if (gc + 3 <= XDIM - 1) {
            v4 = *reinterpret_cast<const float4*>(rp + gc);
        } else {
            int e0 = gc     < XDIM ? gc     : XDIM - 1;
            int e1 = gc + 1 < XDIM ? gc + 1 : XDIM - 1;
            int e2 = gc + 2 < XDIM ? gc + 2 : XDIM - 1;
            int e3 = gc + 3 < XDIM ? gc + 3 : XDIM - 1;
            v4 = make_float4(rp[e0], rp[e1], rp[e2], rp[e3]);
        }
        int e4 = gc + 4 < XDIM ? gc + 4 : XDIM - 1;
        v1 = rp[e4];
    };

    auto issue = [&](int p) {
        int ch = (int)(((unsigned)p * 2731u) >> 14);   // p/6 for p<24
        int q  = p - 6 * ch;
        ld1(q, ch, lane,       pf0, pe0);
        ld1(q, ch, lane + 64,  pf1, pe1);
        if (lane < 32) ld1(q, ch, lane + 128, pf2, pe2);
    };

    auto w1 = [&](uint2* buf, int it, const float4& v4, float v1) {
        unsigned int row = (unsigned int)it / 20u;
        int iw = it - (int)row * 20;
        unsigned int P0 = packx(v4.x), P1 = packx(v4.y), P2 = packx(v4.z),
                     P3 = packx(v4.w), P4 = packx(v1);
        int s   = (iw & 7) << 1;
        int sl0 = (4 * iw)     ^ s;
        int sl2 = (4 * iw + 2) ^ s;
        uint2* bb = buf + row * WPC;
        *reinterpret_cast<uint4*>(bb + sl0) = make_uint4(P0, P1, P1, P2);
        *reinterpret_cast<uint4*>(bb + sl2) = make_uint4(P2, P3, P3, P4);
    };

    auto wrt = [&](int p) {
        uint2* buf = &wbuf[wv][p & 1][0][0];
        w1(buf, lane,      pf0, pe0);
        w1(buf, lane + 64, pf1, pe1);
        if (lane < 32) w1(buf, lane + 128, pf2, pe2);
    };

    // ---- phase-0 loads fly under the weight-table build ----
    issue(0);

    // ---------------- weight tables + Skk (once per block) ----------------
    {
        float k0 = kern[tid], k1 = kern[256 + tid], k2 = kern[512 + tid], k3 = kern[768 + tid];
        float a  = k3 * (1.0f / 255.0f);
        float om = 1.0f - a;
        float w  = om * om;
        int i = tid >> 4, j = tid & 15;
        unsigned int wlo = (unsigned int)bfbits(w);
        wt[0][i * 20 + j] = ((unsigned int)bfbits(-2.0f * w * k0) << 16) | wlo;
        wt[1][i * 20 + j] = ((unsigned int)bfbits(-2.0f * w * k1) << 16) | wlo;
        wt[2][i * 20 + j] = ((unsigned int)bfbits(-2.0f * w * k2) << 16) | wlo;
        wt[3][i * 20 + j] = ((unsigned int)bfbits(-2.0f * w * k3) << 16) | wlo;
        if (tid < 80) {                       // zero row 16 of each channel table
            int c = tid / 20, wd = tid % 20;
            wt[c][16 * 20 + wd] = 0u;
        }
        float4* red = reinterpret_cast<float4*>(&wbuf[0][0][0][0]);   // scratch
        red[tid] = make_float4(w*k0*k0, w*k1*k1, w*k2*k2, w*k3*k3);
        __syncthreads();
        #pragma unroll
        for (int s = 128; s > 0; s >>= 1) {
            if (tid < s) {
                float4 o = red[tid + s], m = red[tid];
                m.x += o.x; m.y += o.y; m.z += o.z; m.w += o.w;
                red[tid] = m;
            }
            __syncthreads();
        }
        if (tid == 0) {
            float4 r0v = red[0];
            skkArr[0] = r0v.x; skkArr[1] = r0v.y; skkArr[2] = r0v.z; skkArr[3] = r0v.w;
        }
        __syncthreads();   // LAST barrier: wt/skk visible, scratch done
    }

    // ---- prologue: buf0 = phase 0; phase-1 loads in flight ----
    wrt(0);
    issue(1);

    f32x16 acc0, acc1, psum0, psum1;
    #pragma unroll
    for (int q = 0; q < 16; ++q) { psum0[q] = 0.0f; psum1[q] = 0.0f; }

    // B-read pair slots are ip-invariant and wave-LOCAL now (no wvoff).
    const int xb = nn + 4 * hf;
    const int b0 = slz(xb),      b1 = slz(xb + 2);
    const int b2 = slz(xb + 8),  b3 = slz(xb + 10);
    const int b4 = slz(xb + 32), b5 = slz(xb + 34);
    const int b6 = slz(xb + 40), b7 = slz(xb + 42);

    for (int p = 0; p < NPH; ++p) {
        int ch = (int)(((unsigned)p * 2731u) >> 14);
        int q  = p - 6 * ch;

        if (q == 0) {
            #pragma unroll
            for (int t = 0; t < 16; ++t) { acc0[t] = 0.0f; acc1[t] = 0.0f; }
        }

        const unsigned int* __restrict__ wch = &wt[ch][0];
        const uint2* __restrict__ bbase = &wbuf[wv][p & 1][0][0];

        #pragma unroll
        for (int r = 0; r < PH; ++r) {
            int ip = q * PH + r;
            if (ip < 47) {
                unsigned int d = (unsigned int)(ip - nn);
                unsigned int wrow = (d > 15u) ? 16u : d;
                U128 alo, ahi;
                alo.u = *reinterpret_cast<const uint4*>(wch + wrow * 20 + hf * 4);
                ahi.u = *reinterpret_cast<const uint4*>(wch + wrow * 20 + 8 + hf * 4);

                const uint2* __restrict__ bp = bbase + r * WPC;
                U128 blo0, bhi0, blo1, bhi1;
                { uint2 a0 = bp[b0], a1 = bp[b1]; blo0.u = make_uint4(a0.x, a0.y, a1.x, a1.y); }
                { uint2 a0 = bp[b2], a1 = bp[b3]; bhi0.u = make_uint4(a0.x, a0.y, a1.x, a1.y); }
                { uint2 a0 = bp[b4], a1 = bp[b5]; blo1.u = make_uint4(a0.x, a0.y, a1.x, a1.y); }
                { uint2 a0 = bp[b6], a1 = bp[b7]; bhi1.u = make_uint4(a0.x, a0.y, a1.x, a1.y); }

                acc0 = __builtin_amdgcn_mfma_f32_32x32x16_bf16(alo.v, blo0.v, acc0, 0, 0, 0);
                acc0 = __builtin_amdgcn_mfma_f32_32x32x16_bf16(ahi.v, bhi0.v, acc0, 0, 0, 0);
                acc1 = __builtin_amdgcn_mfma_f32_32x32x16_bf16(alo.v, blo1.v, acc1, 0, 0, 0);
                acc1 = __builtin_amdgcn_mfma_f32_32x32x16_bf16(ahi.v, bhi1.v, acc1, 0, 0, 0);
            }
        }

        if (q == 5) {                     // channel epilogue
            float sk = skkArr[ch];
            #pragma unroll
            for (int t = 0; t < 16; ++t) {
                float m0 = (acc0[t] + sk) * (1.0f / 256.0f);
                float m1 = (acc1[t] + sk) * (1.0f / 256.0f);
                psum0[t] += __log2f(m0);
                psum1[t] += __log2f(m1);
            }
        }

        // ---- per-wave pipeline: pack next phase, launch loads for p+2 ----
        if (p + 1 < NPH) wrt(p + 1);
        if (p + 2 < NPH) issue(p + 2);
    }

    // psnr = 20log10(255) - 2.5 * sum_c log10(mse_c);  log10 = log2 * 0.30103
    const float BASE = 48.130803608679344f;
    const float SC   = 2.5f * 0.3010299956639812f;
    const int col0 = c0w + nn;
    const int col1 = col0 + 32;
    #pragma unroll
    for (int t = 0; t < 16; ++t) {
        int row = r0 + (t & 3) + ((t >> 2) << 3) + (hf << 2);
        if (row < OW) {
            float* orow = out + (size_t)row * OW;
            if (col0 < OW) orow[col0] = BASE - SC * psum0[t];
            if (col1 < OW) orow[col1] = BASE - SC * psum1[t];
        }
    }
}

extern "C" void kernel_launch(void* const* d_in, const int* in_sizes, int n_in,
                              void* d_out, int out_size, void* d_ws, size_t ws_size,
                              hipStream_t stream) {
    (void)in_sizes; (void)n_in; (void)d_ws; (void)ws_size; (void)out_size;
    const float* x    = (const float*)d_in[0];
    const float* kern = (const float*)d_in[1];
    float* out        = (float*)d_out;

    dim3 grid(XDIM / TC, (OW + TR - 1) / TR);   // 8 x 64 = 512 blocks
    psnr_mfma_kernel<<<grid, 256, 0, stream>>>(x, kern, out);
}

// Round 12
// 64.617 us; speedup vs baseline: 1.1453x; 1.1453x over previous
//
#include <hip/hip_runtime.h>
#include <hip/hip_bf16.h>
#include <math.h>

#define XDIM 2048
#define OW   2033        // 2048 - 16 + 1
#define TR   32          // out rows per block tile
#define TC   256         // out cols per block tile
#define XWP  272         // staged pair-cols per image row (TC + 16)
#define PH   16          // rows per staging phase (3 x 16 = 48 rows incl. zero-weight ip=47)
#define NP   12          // 4 channels * 3 phases

typedef __bf16 bf16x8 __attribute__((ext_vector_type(8)));
typedef float  f32x16 __attribute__((ext_vector_type(16)));

union U128 { uint4 u; bf16x8 v; };

__device__ __forceinline__ unsigned short bfbits(float f) {
    return __builtin_bit_cast(unsigned short, __float2bfloat16(f));
}
// pair word: low16 = bf16(x^2) (weight w), high16 = bf16(x) (weight -2wk)
__device__ __forceinline__ unsigned int packx(float f) {
    unsigned int r;
    asm("v_cvt_pk_bf16_f32 %0, %1, %2" : "=v"(r) : "v"(f * f), "v"(f));
    return r;
}
// XOR bank swizzle on PAIR index (bits 1..3 only): 16B write alignment kept,
// bijective; r9/r10-proven conflict-clean for writes AND b64 reads.
__device__ __forceinline__ int slz(int c) { return c ^ (((c >> 2) & 7) << 1); }

__global__ __launch_bounds__(256) void psnr_mfma_kernel(
    const float* __restrict__ x,
    const float* __restrict__ kern,
    float* __restrict__ out)
{
    // Double-buffered 16-row pair tiles (r10 structure, 79us): compute(p) on
    // buf[p&1] overlaps write(p+1) on buf[(p+1)&1]; ONE barrier per phase.
    // THIS ROUND: all phases uniform 16 ips + fully-unrolled inner loop so the
    // compiler software-pipelines ds_read -> MFMA with counted lgkmcnt.
    __shared__ __align__(16) uint2 xtp[2][PH][XWP];               // 69.6 KB
    __shared__ __align__(16) unsigned int wt[4][17 * 20];         // 5.44 KB
    __shared__ float skkArr[4];

    const int tid  = threadIdx.x;
    const int lane = tid & 63;
    const int wv   = tid >> 6;         // wave 0..3
    const int nn   = lane & 31;        // m for A-frags, n for B-frags
    const int hf   = lane >> 5;        // k-block half

    const int r0 = blockIdx.y * TR;
    const int c0 = blockIdx.x * TC;

    // ---- phase staging register set: 5 float4 + 5 float (~25 VGPR) ----
    float4 pf[5];
    float  pe[5];

    auto issue = [&](int p) {
        int ch = p / 3, ph = p - 3 * ch;
        const float* __restrict__ xc = x + ((size_t)ch << 22);
        const int rbase = r0 + ph * PH;
        #pragma unroll
        for (int t = 0; t < 5; ++t) {
            int idx = tid + 256 * t;
            if (idx < PH * 68) {
                int row = idx / 68;
                int it  = idx - row * 68;
                int gr  = rbase + row; if (gr > XDIM - 1) gr = XDIM - 1;
                int gc  = c0 + it * 4;
                const float* rp = xc + (size_t)gr * XDIM;
                if (gc + 3 <= XDIM - 1) {
                    pf[t] = *reinterpret_cast<const float4*>(rp + gc);
                } else {
                    int e0 = gc     < XDIM ? gc     : XDIM - 1;
                    int e1 = gc + 1 < XDIM ? gc + 1 : XDIM - 1;
                    int e2 = gc + 2 < XDIM ? gc + 2 : XDIM - 1;
                    int e3 = gc + 3 < XDIM ? gc + 3 : XDIM - 1;
                    pf[t] = make_float4(rp[e0], rp[e1], rp[e2], rp[e3]);
                }
                int e4 = gc + 4 < XDIM ? gc + 4 : XDIM - 1;
                pe[t] = rp[e4];
            }
        }
    };

    auto wrt = [&](int p) {
        uint2* __restrict__ buf = &xtp[p & 1][0][0];
        #pragma unroll
        for (int t = 0; t < 5; ++t) {
            int idx = tid + 256 * t;
            if (idx < PH * 68) {
                int row = idx / 68;
                int it  = idx - row * 68;
                float4 v = pf[t];
                unsigned int P0 = packx(v.x), P1 = packx(v.y), P2 = packx(v.z),
                             P3 = packx(v.w), P4 = packx(pe[t]);
                int s   = (it & 7) << 1;
                int sl0 = (4 * it)     ^ s;
                int sl2 = (4 * it + 2) ^ s;
                uint2* bb = buf + row * XWP;
                *reinterpret_cast<uint4*>(bb + sl0) = make_uint4(P0, P1, P1, P2);
                *reinterpret_cast<uint4*>(bb + sl2) = make_uint4(P2, P3, P3, P4);
            }
        }
    };

    // ---- phase-0 loads fly under the weight-table build ----
    issue(0);

    // ---------------- weight tables + Skk (once per block) ----------------
    {
        float k0 = kern[tid], k1 = kern[256 + tid], k2 = kern[512 + tid], k3 = kern[768 + tid];
        float a  = k3 * (1.0f / 255.0f);
        float om = 1.0f - a;
        float w  = om * om;
        int i = tid >> 4, j = tid & 15;
        unsigned int wlo = (unsigned int)bfbits(w);
        wt[0][i * 20 + j] = ((unsigned int)bfbits(-2.0f * w * k0) << 16) | wlo;
        wt[1][i * 20 + j] = ((unsigned int)bfbits(-2.0f * w * k1) << 16) | wlo;
        wt[2][i * 20 + j] = ((unsigned int)bfbits(-2.0f * w * k2) << 16) | wlo;
        wt[3][i * 20 + j] = ((unsigned int)bfbits(-2.0f * w * k3) << 16) | wlo;
        if (tid < 80) {                       // zero row 16 of each channel table
            int c = tid / 20, wd = tid % 20;
            wt[c][16 * 20 + wd] = 0u;
        }
        float4* red = reinterpret_cast<float4*>(&xtp[0][0][0]);   // scratch pre-staging
        red[tid] = make_float4(w*k0*k0, w*k1*k1, w*k2*k2, w*k3*k3);
        __syncthreads();
        #pragma unroll
        for (int s = 128; s > 0; s >>= 1) {
            if (tid < s) {
                float4 o = red[tid + s], m = red[tid];
                m.x += o.x; m.y += o.y; m.z += o.z; m.w += o.w;
                red[tid] = m;
            }
            __syncthreads();
        }
        if (tid == 0) {
            float4 r0v = red[0];
            skkArr[0] = r0v.x; skkArr[1] = r0v.y; skkArr[2] = r0v.z; skkArr[3] = r0v.w;
        }
        __syncthreads();
    }

    // ---- pipeline prologue: buf0 = phase 0; phase-1 loads in flight ----
    wrt(0);
    issue(1);
    __syncthreads();

    f32x16 acc0, acc1, psum0, psum1;
    #pragma unroll
    for (int q = 0; q < 16; ++q) { psum0[q] = 0.0f; psum1[q] = 0.0f; }

    // B-read pair slots are ip-invariant: swizzle once (slz(c+64)=slz(c)+64).
    const int xbase = nn + 4 * hf;
    const int wvoff = (wv << 6);
    const int p0 = slz(xbase)      + wvoff, p1 = slz(xbase + 2)  + wvoff;
    const int p2 = slz(xbase + 8)  + wvoff, p3 = slz(xbase + 10) + wvoff;
    const int p4 = slz(xbase + 32) + wvoff, p5 = slz(xbase + 34) + wvoff;
    const int p6 = slz(xbase + 40) + wvoff, p7 = slz(xbase + 42) + wvoff;

    for (int p = 0; p < NP; ++p) {
        const int ch  = p / 3;
        const int ph  = p - 3 * ch;

        if (ph == 0) {
            #pragma unroll
            for (int q = 0; q < 16; ++q) { acc0[q] = 0.0f; acc1[q] = 0.0f; }
        }

        // ---- compute phase p from buf[p&1]: UNIFORM 16 ips, FULLY UNROLLED.
        // ip = 47 has an all-zero weight row -> contributes 0 (row 47 staged).
        const unsigned int* __restrict__ wch = &wt[ch][0];
        const uint2* __restrict__ bbase = &xtp[p & 1][0][0];
        #pragma unroll
        for (int r = 0; r < PH; ++r) {
            int ip = ph * PH + r;
            unsigned int d = (unsigned int)(ip - nn);
            unsigned int wrow = (d > 15u) ? 16u : d;
            U128 alo, ahi;
            alo.u = *reinterpret_cast<const uint4*>(wch + wrow * 20 + hf * 4);
            ahi.u = *reinterpret_cast<const uint4*>(wch + wrow * 20 + 8 + hf * 4);

            const uint2* __restrict__ bp = bbase + r * XWP;
            U128 blo0, bhi0, blo1, bhi1;
            { uint2 a0 = bp[p0], a1 = bp[p1]; blo0.u = make_uint4(a0.x, a0.y, a1.x, a1.y); }
            { uint2 a0 = bp[p2], a1 = bp[p3]; bhi0.u = make_uint4(a0.x, a0.y, a1.x, a1.y); }
            { uint2 a0 = bp[p4], a1 = bp[p5]; blo1.u = make_uint4(a0.x, a0.y, a1.x, a1.y); }
            { uint2 a0 = bp[p6], a1 = bp[p7]; bhi1.u = make_uint4(a0.x, a0.y, a1.x, a1.y); }

            acc0 = __builtin_amdgcn_mfma_f32_32x32x16_bf16(alo.v, blo0.v, acc0, 0, 0, 0);
            acc0 = __builtin_amdgcn_mfma_f32_32x32x16_bf16(ahi.v, bhi0.v, acc0, 0, 0, 0);
            acc1 = __builtin_amdgcn_mfma_f32_32x32x16_bf16(alo.v, blo1.v, acc1, 0, 0, 0);
            acc1 = __builtin_amdgcn_mfma_f32_32x32x16_bf16(ahi.v, bhi1.v, acc1, 0, 0, 0);
        }

        if (ph == 2) {                     // channel epilogue
            float sk = skkArr[ch];
            #pragma unroll
            for (int q = 0; q < 16; ++q) {
                float m0 = (acc0[q] + sk) * (1.0f / 256.0f);
                float m1 = (acc1[q] + sk) * (1.0f / 256.0f);
                psum0[q] += __log2f(m0);
                psum1[q] += __log2f(m1);
            }
        }

        // ---- pipeline: write phase p+1, launch loads for p+2, ONE barrier ----
        if (p + 1 < NP) {
            wrt(p + 1);
            if (p + 2 < NP) issue(p + 2);
            __syncthreads();
        }
    }

    // psnr = 20log10(255) - 2.5 * sum_c log10(mse_c);  log10 = log2 * 0.30103
    const float BASE = 48.130803608679344f;
    const float SC   = 2.5f * 0.3010299956639812f;
    const int col0 = c0 + (wv << 6) + nn;
    const int col1 = col0 + 32;
    #pragma unroll
    for (int q = 0; q < 16; ++q) {
        int row = r0 + (q & 3) + ((q >> 2) << 3) + (hf << 2);
        if (row < OW) {
            float* orow = out + (size_t)row * OW;
            if (col0 < OW) orow[col0] = BASE - SC * psum0[q];
            if (col1 < OW) orow[col1] = BASE - SC * psum1[q];
        }
    }
}

extern "C" void kernel_launch(void* const* d_in, const int* in_sizes, int n_in,
                              void* d_out, int out_size, void* d_ws, size_t ws_size,
                              hipStream_t stream) {
    (void)in_sizes; (void)n_in; (void)d_ws; (void)ws_size; (void)out_size;
    const float* x    = (const float*)d_in[0];
    const float* kern = (const float*)d_in[1];
    float* out        = (float*)d_out;

    dim3 grid(XDIM / TC, (OW + TR - 1) / TR);   // 8 x 64 = 512 blocks
    psnr_mfma_kernel<<<grid, 256, 0, stream>>>(x, kern, out);
}

// Round 13
// 64.238 us; speedup vs baseline: 1.1521x; 1.0059x over previous
//
#include <hip/hip_runtime.h>
#include <hip/hip_bf16.h>
#include <math.h>

#define XDIM 2048
#define OW   2033        // 2048 - 16 + 1
#define TR   32          // out rows per block tile
#define TC   256         // out cols per block tile
#define XWP  272         // staged pair-cols per image row (TC + 16)
#define PH   16          // rows per staging phase (3 x 16 = 48 rows incl. zero-weight ip=47)
#define NP   12          // 4 channels * 3 phases

typedef __bf16 bf16x8 __attribute__((ext_vector_type(8)));
typedef float  f32x16 __attribute__((ext_vector_type(16)));

union U128 { uint4 u; bf16x8 v; };

__device__ __forceinline__ unsigned short bfbits(float f) {
    return __builtin_bit_cast(unsigned short, __float2bfloat16(f));
}
// pair word: low16 = bf16(x^2) (weight w), high16 = bf16(x) (weight -2wk)
__device__ __forceinline__ unsigned int packx(float f) {
    unsigned int r;
    asm("v_cvt_pk_bf16_f32 %0, %1, %2" : "=v"(r) : "v"(f * f), "v"(f));
    return r;
}
// XOR bank swizzle on PAIR index (bits 1..3 only): 16B write alignment kept,
// bijective; r9-r12-proven conflict-clean for writes AND b64 reads.
__device__ __forceinline__ int slz(int c) { return c ^ (((c >> 2) & 7) << 1); }

__global__ __launch_bounds__(256) void psnr_mfma_kernel(
    const float* __restrict__ x,
    const float* __restrict__ kern,
    float* __restrict__ out)
{
    // r12 structure (76us): double-buffered 16-row pair tiles, uniform 16-ip
    // fully-unrolled phases, ONE barrier per phase.
    // THIS ROUND: (1) s_setprio(1) around the MFMA cluster so compute-phase
    // waves win CU arbitration over the co-resident block's staging waves;
    // (2) wrt/issue hoisted BEFORE compute so the barrier drain finds the
    // ds_writes already retired and VMEM gets a full phase of flight.
    __shared__ __align__(16) uint2 xtp[2][PH][XWP];               // 69.6 KB
    __shared__ __align__(16) unsigned int wt[4][17 * 20];         // 5.44 KB
    __shared__ float skkArr[4];

    const int tid  = threadIdx.x;
    const int lane = tid & 63;
    const int wv   = tid >> 6;         // wave 0..3
    const int nn   = lane & 31;        // m for A-frags, n for B-frags
    const int hf   = lane >> 5;        // k-block half

    const int r0 = blockIdx.y * TR;
    const int c0 = blockIdx.x * TC;

    // ---- phase staging register set: 5 float4 + 5 float (~25 VGPR) ----
    float4 pf[5];
    float  pe[5];

    auto issue = [&](int p) {
        int ch = p / 3, ph = p - 3 * ch;
        const float* __restrict__ xc = x + ((size_t)ch << 22);
        const int rbase = r0 + ph * PH;
        #pragma unroll
        for (int t = 0; t < 5; ++t) {
            int idx = tid + 256 * t;
            if (idx < PH * 68) {
                int row = idx / 68;
                int it  = idx - row * 68;
                int gr  = rbase + row; if (gr > XDIM - 1) gr = XDIM - 1;
                int gc  = c0 + it * 4;
                const float* rp = xc + (size_t)gr * XDIM;
                if (gc + 3 <= XDIM - 1) {
                    pf[t] = *reinterpret_cast<const float4*>(rp + gc);
                } else {
                    int e0 = gc     < XDIM ? gc     : XDIM - 1;
                    int e1 = gc + 1 < XDIM ? gc + 1 : XDIM - 1;
                    int e2 = gc + 2 < XDIM ? gc + 2 : XDIM - 1;
                    int e3 = gc + 3 < XDIM ? gc + 3 : XDIM - 1;
                    pf[t] = make_float4(rp[e0], rp[e1], rp[e2], rp[e3]);
                }
                int e4 = gc + 4 < XDIM ? gc + 4 : XDIM - 1;
                pe[t] = rp[e4];
            }
        }
    };

    auto wrt = [&](int p) {
        uint2* __restrict__ buf = &xtp[p & 1][0][0];
        #pragma unroll
        for (int t = 0; t < 5; ++t) {
            int idx = tid + 256 * t;
            if (idx < PH * 68) {
                int row = idx / 68;
                int it  = idx - row * 68;
                float4 v = pf[t];
                unsigned int P0 = packx(v.x), P1 = packx(v.y), P2 = packx(v.z),
                             P3 = packx(v.w), P4 = packx(pe[t]);
                int s   = (it & 7) << 1;
                int sl0 = (4 * it)     ^ s;
                int sl2 = (4 * it + 2) ^ s;
                uint2* bb = buf + row * XWP;
                *reinterpret_cast<uint4*>(bb + sl0) = make_uint4(P0, P1, P1, P2);
                *reinterpret_cast<uint4*>(bb + sl2) = make_uint4(P2, P3, P3, P4);
            }
        }
    };

    // ---- phase-0 loads fly under the weight-table build ----
    issue(0);

    // ---------------- weight tables + Skk (once per block) ----------------
    {
        float k0 = kern[tid], k1 = kern[256 + tid], k2 = kern[512 + tid], k3 = kern[768 + tid];
        float a  = k3 * (1.0f / 255.0f);
        float om = 1.0f - a;
        float w  = om * om;
        int i = tid >> 4, j = tid & 15;
        unsigned int wlo = (unsigned int)bfbits(w);
        wt[0][i * 20 + j] = ((unsigned int)bfbits(-2.0f * w * k0) << 16) | wlo;
        wt[1][i * 20 + j] = ((unsigned int)bfbits(-2.0f * w * k1) << 16) | wlo;
        wt[2][i * 20 + j] = ((unsigned int)bfbits(-2.0f * w * k2) << 16) | wlo;
        wt[3][i * 20 + j] = ((unsigned int)bfbits(-2.0f * w * k3) << 16) | wlo;
        if (tid < 80) {                       // zero row 16 of each channel table
            int c = tid / 20, wd = tid % 20;
            wt[c][16 * 20 + wd] = 0u;
        }
        float4* red = reinterpret_cast<float4*>(&xtp[0][0][0]);   // scratch pre-staging
        red[tid] = make_float4(w*k0*k0, w*k1*k1, w*k2*k2, w*k3*k3);
        __syncthreads();
        #pragma unroll
        for (int s = 128; s > 0; s >>= 1) {
            if (tid < s) {
                float4 o = red[tid + s], m = red[tid];
                m.x += o.x; m.y += o.y; m.z += o.z; m.w += o.w;
                red[tid] = m;
            }
            __syncthreads();
        }
        if (tid == 0) {
            float4 r0v = red[0];
            skkArr[0] = r0v.x; skkArr[1] = r0v.y; skkArr[2] = r0v.z; skkArr[3] = r0v.w;
        }
        __syncthreads();
    }

    // ---- pipeline prologue: buf0 = phase 0; phase-1 loads in flight ----
    wrt(0);
    issue(1);
    __syncthreads();

    f32x16 acc0, acc1, psum0, psum1;
    #pragma unroll
    for (int q = 0; q < 16; ++q) { psum0[q] = 0.0f; psum1[q] = 0.0f; }

    // B-read pair slots are ip-invariant: swizzle once (slz(c+64)=slz(c)+64).
    const int xbase = nn + 4 * hf;
    const int wvoff = (wv << 6);
    const int p0 = slz(xbase)      + wvoff, p1 = slz(xbase + 2)  + wvoff;
    const int p2 = slz(xbase + 8)  + wvoff, p3 = slz(xbase + 10) + wvoff;
    const int p4 = slz(xbase + 32) + wvoff, p5 = slz(xbase + 34) + wvoff;
    const int p6 = slz(xbase + 40) + wvoff, p7 = slz(xbase + 42) + wvoff;

    for (int p = 0; p < NP; ++p) {
        const int ch  = p / 3;
        const int ph  = p - 3 * ch;

        // ---- staging first: writes retire during compute; loads fly a full
        // phase + compute before their wrt. (Race-free: all reads of
        // buf[(p+1)&1] finished before the previous barrier.)
        if (p + 1 < NP) wrt(p + 1);
        if (p + 2 < NP) issue(p + 2);

        if (ph == 0) {
            #pragma unroll
            for (int q = 0; q < 16; ++q) { acc0[q] = 0.0f; acc1[q] = 0.0f; }
        }

        // ---- compute phase p from buf[p&1]: uniform 16 ips, fully unrolled,
        // priority-boosted (T5). ip = 47 hits the all-zero weight row.
        const unsigned int* __restrict__ wch = &wt[ch][0];
        const uint2* __restrict__ bbase = &xtp[p & 1][0][0];
        __builtin_amdgcn_s_setprio(1);
        #pragma unroll
        for (int r = 0; r < PH; ++r) {
            int ip = ph * PH + r;
            unsigned int d = (unsigned int)(ip - nn);
            unsigned int wrow = (d > 15u) ? 16u : d;
            U128 alo, ahi;
            alo.u = *reinterpret_cast<const uint4*>(wch + wrow * 20 + hf * 4);
            ahi.u = *reinterpret_cast<const uint4*>(wch + wrow * 20 + 8 + hf * 4);

            const uint2* __restrict__ bp = bbase + r * XWP;
            U128 blo0, bhi0, blo1, bhi1;
            { uint2 a0 = bp[p0], a1 = bp[p1]; blo0.u = make_uint4(a0.x, a0.y, a1.x, a1.y); }
            { uint2 a0 = bp[p2], a1 = bp[p3]; bhi0.u = make_uint4(a0.x, a0.y, a1.x, a1.y); }
            { uint2 a0 = bp[p4], a1 = bp[p5]; blo1.u = make_uint4(a0.x, a0.y, a1.x, a1.y); }
            { uint2 a0 = bp[p6], a1 = bp[p7]; bhi1.u = make_uint4(a0.x, a0.y, a1.x, a1.y); }

            acc0 = __builtin_amdgcn_mfma_f32_32x32x16_bf16(alo.v, blo0.v, acc0, 0, 0, 0);
            acc0 = __builtin_amdgcn_mfma_f32_32x32x16_bf16(ahi.v, bhi0.v, acc0, 0, 0, 0);
            acc1 = __builtin_amdgcn_mfma_f32_32x32x16_bf16(alo.v, blo1.v, acc1, 0, 0, 0);
            acc1 = __builtin_amdgcn_mfma_f32_32x32x16_bf16(ahi.v, bhi1.v, acc1, 0, 0, 0);
        }
        __builtin_amdgcn_s_setprio(0);

        if (ph == 2) {                     // channel epilogue
            float sk = skkArr[ch];
            #pragma unroll
            for (int q = 0; q < 16; ++q) {
                float m0 = (acc0[q] + sk) * (1.0f / 256.0f);
                float m1 = (acc1[q] + sk) * (1.0f / 256.0f);
                psum0[q] += __log2f(m0);
                psum1[q] += __log2f(m1);
            }
        }

        if (p + 1 < NP) __syncthreads();
    }

    // psnr = 20log10(255) - 2.5 * sum_c log10(mse_c);  log10 = log2 * 0.30103
    const float BASE = 48.130803608679344f;
    const float SC   = 2.5f * 0.3010299956639812f;
    const int col0 = c0 + (wv << 6) + nn;
    const int col1 = col0 + 32;
    #pragma unroll
    for (int q = 0; q < 16; ++q) {
        int row = r0 + (q & 3) + ((q >> 2) << 3) + (hf << 2);
        if (row < OW) {
            float* orow = out + (size_t)row * OW;
            if (col0 < OW) orow[col0] = BASE - SC * psum0[q];
            if (col1 < OW) orow[col1] = BASE - SC * psum1[q];
        }
    }
}

extern "C" void kernel_launch(void* const* d_in, const int* in_sizes, int n_in,
                              void* d_out, int out_size, void* d_ws, size_t ws_size,
                              hipStream_t stream) {
    (void)in_sizes; (void)n_in; (void)d_ws; (void)ws_size; (void)out_size;
    const float* x    = (const float*)d_in[0];
    const float* kern = (const float*)d_in[1];
    float* out        = (float*)d_out;

    dim3 grid(XDIM / TC, (OW + TR - 1) / TR);   // 8 x 64 = 512 blocks
    psnr_mfma_kernel<<<grid, 256, 0, stream>>>(x, kern, out);
}

// Round 14
// 64.023 us; speedup vs baseline: 1.1560x; 1.0034x over previous
//
#include <hip/hip_runtime.h>
#include <hip/hip_bf16.h>
#include <math.h>

#define XDIM 2048
#define OW   2033        // 2048 - 16 + 1
#define TR   32          // out rows per block tile
#define TC   256         // out cols per block tile
#define XWP  272         // staged pair-cols per image row (TC + 16)
#define PH   16          // rows per staging phase (3 x 16 = 48 rows incl. zero-weight ip=47)
#define NP   12          // 4 channels * 3 phases

typedef __bf16 bf16x8 __attribute__((ext_vector_type(8)));
typedef float  f32x16 __attribute__((ext_vector_type(16)));

union U128 { uint4 u; bf16x8 v; };

__device__ __forceinline__ unsigned short bfbits(float f) {
    return __builtin_bit_cast(unsigned short, __float2bfloat16(f));
}
// pair word: low16 = bf16(x^2) (weight w), high16 = bf16(x) (weight -2wk)
__device__ __forceinline__ unsigned int packx(float f) {
    unsigned int r;
    asm("v_cvt_pk_bf16_f32 %0, %1, %2" : "=v"(r) : "v"(f * f), "v"(f));
    return r;
}
// XOR bank swizzle on PAIR index (bits 1..3 only): 16B write alignment kept,
// bijective; r9-r12-proven conflict-clean for writes AND b64 reads.
__device__ __forceinline__ int slz(int c) { return c ^ (((c >> 2) & 7) << 1); }

__global__ __launch_bounds__(256) void psnr_mfma_kernel(
    const float* __restrict__ x,
    const float* __restrict__ kern,
    float* __restrict__ out)
{
    // r12 structure (76us): double-buffered 16-row pair tiles, uniform 16-ip
    // fully-unrolled phases, ONE barrier per phase.
    // THIS ROUND: (1) s_setprio(1) around the MFMA cluster so compute-phase
    // waves win CU arbitration over the co-resident block's staging waves;
    // (2) wrt/issue hoisted BEFORE compute so the barrier drain finds the
    // ds_writes already retired and VMEM gets a full phase of flight.
    __shared__ __align__(16) uint2 xtp[2][PH][XWP];               // 69.6 KB
    __shared__ __align__(16) unsigned int wt[4][17 * 20];         // 5.44 KB
    __shared__ float skkArr[4];

    const int tid  = threadIdx.x;
    const int lane = tid & 63;
    const int wv   = tid >> 6;         // wave 0..3
    const int nn   = lane & 31;        // m for A-frags, n for B-frags
    const int hf   = lane >> 5;        // k-block half

    const int r0 = blockIdx.y * TR;
    const int c0 = blockIdx.x * TC;

    // ---- phase staging register set: 5 float4 + 5 float (~25 VGPR) ----
    float4 pf[5];
    float  pe[5];

    auto issue = [&](int p) {
        int ch = p / 3, ph = p - 3 * ch;
        const float* __restrict__ xc = x + ((size_t)ch << 22);
        const int rbase = r0 + ph * PH;
        #pragma unroll
        for (int t = 0; t < 5; ++t) {
            int idx = tid + 256 * t;
            if (idx < PH * 68) {
                int row = idx / 68;
                int it  = idx - row * 68;
                int gr  = rbase + row; if (gr > XDIM - 1) gr = XDIM - 1;
                int gc  = c0 + it * 4;
                const float* rp = xc + (size_t)gr * XDIM;
                if (gc + 3 <= XDIM - 1) {
                    pf[t] = *reinterpret_cast<const float4*>(rp + gc);
                } else {
                    int e0 = gc     < XDIM ? gc     : XDIM - 1;
                    int e1 = gc + 1 < XDIM ? gc + 1 : XDIM - 1;
                    int e2 = gc + 2 < XDIM ? gc + 2 : XDIM - 1;
                    int e3 = gc + 3 < XDIM ? gc + 3 : XDIM - 1;
                    pf[t] = make_float4(rp[e0], rp[e1], rp[e2], rp[e3]);
                }
                int e4 = gc + 4 < XDIM ? gc + 4 : XDIM - 1;
                pe[t] = rp[e4];
            }
        }
    };

    auto wrt = [&](int p) {
        uint2* __restrict__ buf = &xtp[p & 1][0][0];
        #pragma unroll
        for (int t = 0; t < 5; ++t) {
            int idx = tid + 256 * t;
            if (idx < PH * 68) {
                int row = idx / 68;
                int it  = idx - row * 68;
                float4 v = pf[t];
                unsigned int P0 = packx(v.x), P1 = packx(v.y), P2 = packx(v.z),
                             P3 = packx(v.w), P4 = packx(pe[t]);
                int s   = (it & 7) << 1;
                int sl0 = (4 * it)     ^ s;
                int sl2 = (4 * it + 2) ^ s;
                uint2* bb = buf + row * XWP;
                *reinterpret_cast<uint4*>(bb + sl0) = make_uint4(P0, P1, P1, P2);
                *reinterpret_cast<uint4*>(bb + sl2) = make_uint4(P2, P3, P3, P4);
            }
        }
    };

    // ---- phase-0 loads fly under the weight-table build ----
    issue(0);

    // ---------------- weight tables + Skk (once per block) ----------------
    {
        float k0 = kern[tid], k1 = kern[256 + tid], k2 = kern[512 + tid], k3 = kern[768 + tid];
        float a  = k3 * (1.0f / 255.0f);
        float om = 1.0f - a;
        float w  = om * om;
        int i = tid >> 4, j = tid & 15;
        unsigned int wlo = (unsigned int)bfbits(w);
        wt[0][i * 20 + j] = ((unsigned int)bfbits(-2.0f * w * k0) << 16) | wlo;
        wt[1][i * 20 + j] = ((unsigned int)bfbits(-2.0f * w * k1) << 16) | wlo;
        wt[2][i * 20 + j] = ((unsigned int)bfbits(-2.0f * w * k2) << 16) | wlo;
        wt[3][i * 20 + j] = ((unsigned int)bfbits(-2.0f * w * k3) << 16) | wlo;
        if (tid < 80) {                       // zero row 16 of each channel table
            int c = tid / 20, wd = tid % 20;
            wt[c][16 * 20 + wd] = 0u;
        }
        float4* red = reinterpret_cast<float4*>(&xtp[0][0][0]);   // scratch pre-staging
        red[tid] = make_float4(w*k0*k0, w*k1*k1, w*k2*k2, w*k3*k3);
        __syncthreads();
        #pragma unroll
        for (int s = 128; s > 0; s >>= 1) {
            if (tid < s) {
                float4 o = red[tid + s], m = red[tid];
                m.x += o.x; m.y += o.y; m.z += o.z; m.w += o.w;
                red[tid] = m;
            }
            __syncthreads();
        }
        if (tid == 0) {
            float4 r0v = red[0];
            skkArr[0] = r0v.x; skkArr[1] = r0v.y; skkArr[2] = r0v.z; skkArr[3] = r0v.w;
        }
        __syncthreads();
    }

    // ---- pipeline prologue: buf0 = phase 0; phase-1 loads in flight ----
    wrt(0);
    issue(1);
    __syncthreads();

    f32x16 acc0, acc1, psum0, psum1;
    #pragma unroll
    for (int q = 0; q < 16; ++q) { psum0[q] = 0.0f; psum1[q] = 0.0f; }

    // B-read pair slots are ip-invariant: swizzle once (slz(c+64)=slz(c)+64).
    const int xbase = nn + 4 * hf;
    const int wvoff = (wv << 6);
    const int p0 = slz(xbase)      + wvoff, p1 = slz(xbase + 2)  + wvoff;
    const int p2 = slz(xbase + 8)  + wvoff, p3 = slz(xbase + 10) + wvoff;
    const int p4 = slz(xbase + 32) + wvoff, p5 = slz(xbase + 34) + wvoff;
    const int p6 = slz(xbase + 40) + wvoff, p7 = slz(xbase + 42) + wvoff;

    for (int p = 0; p < NP; ++p) {
        const int ch  = p / 3;
        const int ph  = p - 3 * ch;

        // ---- staging first: writes retire during compute; loads fly a full
        // phase + compute before their wrt. (Race-free: all reads of
        // buf[(p+1)&1] finished before the previous barrier.)
        if (p + 1 < NP) wrt(p + 1);
        if (p + 2 < NP) issue(p + 2);

        if (ph == 0) {
            #pragma unroll
            for (int q = 0; q < 16; ++q) { acc0[q] = 0.0f; acc1[q] = 0.0f; }
        }

        // ---- compute phase p from buf[p&1]: uniform 16 ips, fully unrolled,
        // priority-boosted (T5). ip = 47 hits the all-zero weight row.
        const unsigned int* __restrict__ wch = &wt[ch][0];
        const uint2* __restrict__ bbase = &xtp[p & 1][0][0];
        __builtin_amdgcn_s_setprio(1);
        #pragma unroll
        for (int r = 0; r < PH; ++r) {
            int ip = ph * PH + r;
            unsigned int d = (unsigned int)(ip - nn);
            unsigned int wrow = (d > 15u) ? 16u : d;
            U128 alo, ahi;
            alo.u = *reinterpret_cast<const uint4*>(wch + wrow * 20 + hf * 4);
            ahi.u = *reinterpret_cast<const uint4*>(wch + wrow * 20 + 8 + hf * 4);

            const uint2* __restrict__ bp = bbase + r * XWP;
            U128 blo0, bhi0, blo1, bhi1;
            { uint2 a0 = bp[p0], a1 = bp[p1]; blo0.u = make_uint4(a0.x, a0.y, a1.x, a1.y); }
            { uint2 a0 = bp[p2], a1 = bp[p3]; bhi0.u = make_uint4(a0.x, a0.y, a1.x, a1.y); }
            { uint2 a0 = bp[p4], a1 = bp[p5]; blo1.u = make_uint4(a0.x, a0.y, a1.x, a1.y); }
            { uint2 a0 = bp[p6], a1 = bp[p7]; bhi1.u = make_uint4(a0.x, a0.y, a1.x, a1.y); }

            acc0 = __builtin_amdgcn_mfma_f32_32x32x16_bf16(alo.v, blo0.v, acc0, 0, 0, 0);
            acc0 = __builtin_amdgcn_mfma_f32_32x32x16_bf16(ahi.v, bhi0.v, acc0, 0, 0, 0);
            acc1 = __builtin_amdgcn_mfma_f32_32x32x16_bf16(alo.v, blo1.v, acc1, 0, 0, 0);
            acc1 = __builtin_amdgcn_mfma_f32_32x32x16_bf16(ahi.v, bhi1.v, acc1, 0, 0, 0);
        }
        __builtin_amdgcn_s_setprio(0);

        if (ph == 2) {                     // channel epilogue
            float sk = skkArr[ch];
            #pragma unroll
            for (int q = 0; q < 16; ++q) {
                float m0 = (acc0[q] + sk) * (1.0f / 256.0f);
                float m1 = (acc1[q] + sk) * (1.0f / 256.0f);
                psum0[q] += __log2f(m0);
                psum1[q] += __log2f(m1);
            }
        }

        if (p + 1 < NP) __syncthreads();
    }

    // psnr = 20log10(255) - 2.5 * sum_c log10(mse_c);  log10 = log2 * 0.30103
    const float BASE = 48.130803608679344f;
    const float SC   = 2.5f * 0.3010299956639812f;
    const int col0 = c0 + (wv << 6) + nn;
    const int col1 = col0 + 32;
    #pragma unroll
    for (int q = 0; q < 16; ++q) {
        int row = r0 + (q & 3) + ((q >> 2) << 3) + (hf << 2);
        if (row < OW) {
            float* orow = out + (size_t)row * OW;
            if (col0 < OW) orow[col0] = BASE - SC * psum0[q];
            if (col1 < OW) orow[col1] = BASE - SC * psum1[q];
        }
    }
}

extern "C" void kernel_launch(void* const* d_in, const int* in_sizes, int n_in,
                              void* d_out, int out_size, void* d_ws, size_t ws_size,
                              hipStream_t stream) {
    (void)in_sizes; (void)n_in; (void)d_ws; (void)ws_size; (void)out_size;
    const float* x    = (const float*)d_in[0];
    const float* kern = (const float*)d_in[1];
    float* out        = (float*)d_out;

    dim3 grid(XDIM / TC, (OW + TR - 1) / TR);   // 8 x 64 = 512 blocks
    psnr_mfma_kernel<<<grid, 256, 0, stream>>>(x, kern, out);
}

// Round 15
// 63.893 us; speedup vs baseline: 1.1583x; 1.0020x over previous
//
#include <hip/hip_runtime.h>
#include <hip/hip_bf16.h>
#include <math.h>

#define XDIM 2048
#define OW   2033        // 2048 - 16 + 1
#define TR   32          // out rows per block tile
#define TC   256         // out cols per block tile
#define XWP  272         // staged pair-cols per image row (TC + 16)
#define PH   16          // rows per staging phase (3 x 16 = 48 rows incl. zero-weight ip=47)
#define NP   12          // 4 channels * 3 phases

typedef __bf16 bf16x8 __attribute__((ext_vector_type(8)));
typedef float  f32x16 __attribute__((ext_vector_type(16)));

union U128 { uint4 u; bf16x8 v; };

__device__ __forceinline__ unsigned short bfbits(float f) {
    return __builtin_bit_cast(unsigned short, __float2bfloat16(f));
}
// pair word: low16 = bf16(x^2) (weight w), high16 = bf16(x) (weight -2wk)
__device__ __forceinline__ unsigned int packx(float f) {
    unsigned int r;
    asm("v_cvt_pk_bf16_f32 %0, %1, %2" : "=v"(r) : "v"(f * f), "v"(f));
    return r;
}
// XOR bank swizzle on PAIR index (bits 1..3 only): 16B write alignment kept,
// bijective; r9-r12-proven conflict-clean for writes AND b64 reads.
__device__ __forceinline__ int slz(int c) { return c ^ (((c >> 2) & 7) << 1); }

__global__ __launch_bounds__(256) void psnr_mfma_kernel(
    const float* __restrict__ x,
    const float* __restrict__ kern,
    float* __restrict__ out)
{
    // r12 structure (76us): double-buffered 16-row pair tiles, uniform 16-ip
    // fully-unrolled phases, ONE barrier per phase.
    // THIS ROUND: (1) s_setprio(1) around the MFMA cluster so compute-phase
    // waves win CU arbitration over the co-resident block's staging waves;
    // (2) wrt/issue hoisted BEFORE compute so the barrier drain finds the
    // ds_writes already retired and VMEM gets a full phase of flight.
    __shared__ __align__(16) uint2 xtp[2][PH][XWP];               // 69.6 KB
    __shared__ __align__(16) unsigned int wt[4][17 * 20];         // 5.44 KB
    __shared__ float skkArr[4];

    const int tid  = threadIdx.x;
    const int lane = tid & 63;
    const int wv   = tid >> 6;         // wave 0..3
    const int nn   = lane & 31;        // m for A-frags, n for B-frags
    const int hf   = lane >> 5;        // k-block half

    const int r0 = blockIdx.y * TR;
    const int c0 = blockIdx.x * TC;

    // ---- phase staging register set: 5 float4 + 5 float (~25 VGPR) ----
    float4 pf[5];
    float  pe[5];

    auto issue = [&](int p) {
        int ch = p / 3, ph = p - 3 * ch;
        const float* __restrict__ xc = x + ((size_t)ch << 22);
        const int rbase = r0 + ph * PH;
        #pragma unroll
        for (int t = 0; t < 5; ++t) {
            int idx = tid + 256 * t;
            if (idx < PH * 68) {
                int row = idx / 68;
                int it  = idx - row * 68;
                int gr  = rbase + row; if (gr > XDIM - 1) gr = XDIM - 1;
                int gc  = c0 + it * 4;
                const float* rp = xc + (size_t)gr * XDIM;
                if (gc + 3 <= XDIM - 1) {
                    pf[t] = *reinterpret_cast<const float4*>(rp + gc);
                } else {
                    int e0 = gc     < XDIM ? gc     : XDIM - 1;
                    int e1 = gc + 1 < XDIM ? gc + 1 : XDIM - 1;
                    int e2 = gc + 2 < XDIM ? gc + 2 : XDIM - 1;
                    int e3 = gc + 3 < XDIM ? gc + 3 : XDIM - 1;
                    pf[t] = make_float4(rp[e0], rp[e1], rp[e2], rp[e3]);
                }
                int e4 = gc + 4 < XDIM ? gc + 4 : XDIM - 1;
                pe[t] = rp[e4];
            }
        }
    };

    auto wrt = [&](int p) {
        uint2* __restrict__ buf = &xtp[p & 1][0][0];
        #pragma unroll
        for (int t = 0; t < 5; ++t) {
            int idx = tid + 256 * t;
            if (idx < PH * 68) {
                int row = idx / 68;
                int it  = idx - row * 68;
                float4 v = pf[t];
                unsigned int P0 = packx(v.x), P1 = packx(v.y), P2 = packx(v.z),
                             P3 = packx(v.w), P4 = packx(pe[t]);
                int s   = (it & 7) << 1;
                int sl0 = (4 * it)     ^ s;
                int sl2 = (4 * it + 2) ^ s;
                uint2* bb = buf + row * XWP;
                *reinterpret_cast<uint4*>(bb + sl0) = make_uint4(P0, P1, P1, P2);
                *reinterpret_cast<uint4*>(bb + sl2) = make_uint4(P2, P3, P3, P4);
            }
        }
    };

    // ---- phase-0 loads fly under the weight-table build ----
    issue(0);

    // ---------------- weight tables + Skk (once per block) ----------------
    {
        float k0 = kern[tid], k1 = kern[256 + tid], k2 = kern[512 + tid], k3 = kern[768 + tid];
        float a  = k3 * (1.0f / 255.0f);
        float om = 1.0f - a;
        float w  = om * om;
        int i = tid >> 4, j = tid & 15;
        unsigned int wlo = (unsigned int)bfbits(w);
        wt[0][i * 20 + j] = ((unsigned int)bfbits(-2.0f * w * k0) << 16) | wlo;
        wt[1][i * 20 + j] = ((unsigned int)bfbits(-2.0f * w * k1) << 16) | wlo;
        wt[2][i * 20 + j] = ((unsigned int)bfbits(-2.0f * w * k2) << 16) | wlo;
        wt[3][i * 20 + j] = ((unsigned int)bfbits(-2.0f * w * k3) << 16) | wlo;
        if (tid < 80) {                       // zero row 16 of each channel table
            int c = tid / 20, wd = tid % 20;
            wt[c][16 * 20 + wd] = 0u;
        }
        float4* red = reinterpret_cast<float4*>(&xtp[0][0][0]);   // scratch pre-staging
        red[tid] = make_float4(w*k0*k0, w*k1*k1, w*k2*k2, w*k3*k3);
        __syncthreads();
        #pragma unroll
        for (int s = 128; s > 0; s >>= 1) {
            if (tid < s) {
                float4 o = red[tid + s], m = red[tid];
                m.x += o.x; m.y += o.y; m.z += o.z; m.w += o.w;
                red[tid] = m;
            }
            __syncthreads();
        }
        if (tid == 0) {
            float4 r0v = red[0];
            skkArr[0] = r0v.x; skkArr[1] = r0v.y; skkArr[2] = r0v.z; skkArr[3] = r0v.w;
        }
        __syncthreads();
    }

    // ---- pipeline prologue: buf0 = phase 0; phase-1 loads in flight ----
    wrt(0);
    issue(1);
    __syncthreads();

    f32x16 acc0, acc1, psum0, psum1;
    #pragma unroll
    for (int q = 0; q < 16; ++q) { psum0[q] = 0.0f; psum1[q] = 0.0f; }

    // B-read pair slots are ip-invariant: swizzle once (slz(c+64)=slz(c)+64).
    const int xbase = nn + 4 * hf;
    const int wvoff = (wv << 6);
    const int p0 = slz(xbase)      + wvoff, p1 = slz(xbase + 2)  + wvoff;
    const int p2 = slz(xbase + 8)  + wvoff, p3 = slz(xbase + 10) + wvoff;
    const int p4 = slz(xbase + 32) + wvoff, p5 = slz(xbase + 34) + wvoff;
    const int p6 = slz(xbase + 40) + wvoff, p7 = slz(xbase + 42) + wvoff;

    for (int p = 0; p < NP; ++p) {
        const int ch  = p / 3;
        const int ph  = p - 3 * ch;

        // ---- staging first: writes retire during compute; loads fly a full
        // phase + compute before their wrt. (Race-free: all reads of
        // buf[(p+1)&1] finished before the previous barrier.)
        if (p + 1 < NP) wrt(p + 1);
        if (p + 2 < NP) issue(p + 2);

        if (ph == 0) {
            #pragma unroll
            for (int q = 0; q < 16; ++q) { acc0[q] = 0.0f; acc1[q] = 0.0f; }
        }

        // ---- compute phase p from buf[p&1]: uniform 16 ips, fully unrolled,
        // priority-boosted (T5). ip = 47 hits the all-zero weight row.
        const unsigned int* __restrict__ wch = &wt[ch][0];
        const uint2* __restrict__ bbase = &xtp[p & 1][0][0];
        __builtin_amdgcn_s_setprio(1);
        #pragma unroll
        for (int r = 0; r < PH; ++r) {
            int ip = ph * PH + r;
            unsigned int d = (unsigned int)(ip - nn);
            unsigned int wrow = (d > 15u) ? 16u : d;
            U128 alo, ahi;
            alo.u = *reinterpret_cast<const uint4*>(wch + wrow * 20 + hf * 4);
            ahi.u = *reinterpret_cast<const uint4*>(wch + wrow * 20 + 8 + hf * 4);

            const uint2* __restrict__ bp = bbase + r * XWP;
            U128 blo0, bhi0, blo1, bhi1;
            { uint2 a0 = bp[p0], a1 = bp[p1]; blo0.u = make_uint4(a0.x, a0.y, a1.x, a1.y); }
            { uint2 a0 = bp[p2], a1 = bp[p3]; bhi0.u = make_uint4(a0.x, a0.y, a1.x, a1.y); }
            { uint2 a0 = bp[p4], a1 = bp[p5]; blo1.u = make_uint4(a0.x, a0.y, a1.x, a1.y); }
            { uint2 a0 = bp[p6], a1 = bp[p7]; bhi1.u = make_uint4(a0.x, a0.y, a1.x, a1.y); }

            acc0 = __builtin_amdgcn_mfma_f32_32x32x16_bf16(alo.v, blo0.v, acc0, 0, 0, 0);
            acc0 = __builtin_amdgcn_mfma_f32_32x32x16_bf16(ahi.v, bhi0.v, acc0, 0, 0, 0);
            acc1 = __builtin_amdgcn_mfma_f32_32x32x16_bf16(alo.v, blo1.v, acc1, 0, 0, 0);
            acc1 = __builtin_amdgcn_mfma_f32_32x32x16_bf16(ahi.v, bhi1.v, acc1, 0, 0, 0);
        }
        __builtin_amdgcn_s_setprio(0);

        if (ph == 2) {                     // channel epilogue
            float sk = skkArr[ch];
            #pragma unroll
            for (int q = 0; q < 16; ++q) {
                float m0 = (acc0[q] + sk) * (1.0f / 256.0f);
                float m1 = (acc1[q] + sk) * (1.0f / 256.0f);
                psum0[q] += __log2f(m0);
                psum1[q] += __log2f(m1);
            }
        }

        if (p + 1 < NP) __syncthreads();
    }

    // psnr = 20log10(255) - 2.5 * sum_c log10(mse_c);  log10 = log2 * 0.30103
    const float BASE = 48.130803608679344f;
    const float SC   = 2.5f * 0.3010299956639812f;
    const int col0 = c0 + (wv << 6) + nn;
    const int col1 = col0 + 32;
    #pragma unroll
    for (int q = 0; q < 16; ++q) {
        int row = r0 + (q & 3) + ((q >> 2) << 3) + (hf << 2);
        if (row < OW) {
            float* orow = out + (size_t)row * OW;
            if (col0 < OW) orow[col0] = BASE - SC * psum0[q];
            if (col1 < OW) orow[col1] = BASE - SC * psum1[q];
        }
    }
}

extern "C" void kernel_launch(void* const* d_in, const int* in_sizes, int n_in,
                              void* d_out, int out_size, void* d_ws, size_t ws_size,
                              hipStream_t stream) {
    (void)in_sizes; (void)n_in; (void)d_ws; (void)ws_size; (void)out_size;
    const float* x    = (const float*)d_in[0];
    const float* kern = (const float*)d_in[1];
    float* out        = (float*)d_out;

    dim3 grid(XDIM / TC, (OW + TR - 1) / TR);   // 8 x 64 = 512 blocks
    psnr_mfma_kernel<<<grid, 256, 0, stream>>>(x, kern, out);
}